// Round 13
// baseline (65.735 us; speedup 1.0000x reference)
//
#include <hip/hip_runtime.h>

#define BATCH   4
#define CIN     64
#define NNODES  4096
#define NEDGES  131072
#define COUT    63
#define NPB     4           // nodes per block in k_main
#define CAP     128         // per-node bucket capacity (deg ~Poisson(32), max ~70)
#define NT      1024        // 16 waves = 4 nodes x 4 batches

// ---------------- k0: zero ncnt + adjsum ------------------------------------
__global__ __launch_bounds__(1024) void k_zero(int* __restrict__ ncnt,
                                               float* __restrict__ adjsum) {
    int i = blockIdx.x * 1024 + threadIdx.x;     // 8 blocks -> 8192 threads
    if (i < NNODES) ncnt[i] = 0;
    else adjsum[i - NNODES] = 0.f;
}

// ---------------- k1: transpose x (b,c,n)->xT (n,b,c)  +  bin edges ---------
// Transpose is HBM-bound (8MB); the edge binning atomics overlap it for free.
__global__ __launch_bounds__(256) void k_pre(const float* __restrict__ x,
                                             const int* __restrict__ src,
                                             const int* __restrict__ dst,
                                             const float* __restrict__ vals,
                                             float* __restrict__ xT,
                                             int* __restrict__ ncnt,
                                             int* __restrict__ gb,
                                             float* __restrict__ adjsum) {
    __shared__ float tile[64][65];   // 65-pad: conflict-free transpose
    int blk = blockIdx.x;            // grid = B * N/64 = 256
    int tid = threadIdx.x;
    int gtid = blk * 256 + tid;

    // edge binning: 2 edges/thread (65536 threads x 2 = 131072)
#pragma unroll
    for (int r = 0; r < 2; ++r) {
        int e = gtid * 2 + r;
        int s = src[e], d = dst[e];
        int p = atomicAdd(&ncnt[s], 1);
        if (p < CAP) gb[(size_t)s * CAP + p] = d;
        atomicAdd(&adjsum[d], vals[e]);
    }

    int b = blk >> 6;
    int n0 = (blk & 63) << 6;
    int tx = tid & 63, ty = tid >> 6;
    const float* xb = x + (size_t)b * CIN * NNODES;
#pragma unroll
    for (int c = ty; c < 64; c += 4)
        tile[c][tx] = xb[(size_t)c * NNODES + n0 + tx];     // coalesced read
    __syncthreads();
#pragma unroll
    for (int n = ty; n < 64; n += 4)                         // 256B row writes
        xT[((size_t)(n0 + n) * BATCH + b) * 64 + tx] = tile[tx][n];
}

// ---------------- k2: gather + dual-GEMM + epilogue -------------------------
// 1024 blocks x 1024 threads; block owns 4 nodes; wave = (node, batch).
// 38KB LDS, <=64 VGPR -> 2 blocks/CU = 32 waves/CU (occupancy cap).
// No barrier between gather and GEMM: wave-local chain, cross-wave overlap.
__global__ __launch_bounds__(NT, 2) void k_main(
    const float* __restrict__ xT,
    const int* __restrict__ gb,
    const int* __restrict__ ncnt,
    const float* __restrict__ adjsum,
    const float* __restrict__ W,
    const float* __restrict__ bias,
    float* __restrict__ out)
{
    __shared__ float w0s[64][64];        // [c][o], o=63 column zeroed (16KB)
    __shared__ float w1s[64][64];        // 16KB
    __shared__ float aggs[NPB][260];     // [node][b*64+c], 260-pad (4.2KB)
    __shared__ int   lists[NPB][CAP];    // per-node dst lists (2KB)

    const int tid  = threadIdx.x;        // 0..1023
    const int wv   = tid >> 6;           // 0..15
    const int lane = tid & 63;
    const int nl   = wv >> 2;            // local node 0..3
    const int b    = wv & 3;             // batch
    const int n    = blockIdx.x * NPB + nl;

    // stage W tiles (cross-wave)
    for (int i = tid; i < 64 * 64; i += NT) {
        int c = i >> 6, o = i & 63;
        float v0 = 0.f, v1 = 0.f;
        if (o < COUT) {
            v0 = W[((size_t)o * CIN + c) * 2 + 0];
            v1 = W[((size_t)o * CIN + c) * 2 + 1];
        }
        w0s[c][o] = v0;
        w1s[c][o] = v1;
    }

    const int cnt = ncnt[n];             // wave-uniform
    const int k1  = min(cnt, CAP);
    // the 4 waves of node nl cooperatively load its list (k = b*64+lane)
    {
        int k = b * 64 + lane;
        if (k < k1) lists[nl][k] = gb[(size_t)n * CAP + k];
    }
    __syncthreads();                     // W tiles + lists ready

    // gather: this wave sums its 256B batch-slice of each neighbor row
    {
        const int* L = lists[nl];
        const float* xb = xT + b * 64 + lane;   // + d*256 per neighbor
        float a0 = 0.f, a1 = 0.f;
        int k = 0;
        for (; k + 8 <= k1; k += 8) {
            float v0 = xb[(size_t)L[k + 0] * 256];
            float v1 = xb[(size_t)L[k + 1] * 256];
            float v2 = xb[(size_t)L[k + 2] * 256];
            float v3 = xb[(size_t)L[k + 3] * 256];
            float v4 = xb[(size_t)L[k + 4] * 256];
            float v5 = xb[(size_t)L[k + 5] * 256];
            float v6 = xb[(size_t)L[k + 6] * 256];
            float v7 = xb[(size_t)L[k + 7] * 256];
            a0 += (v0 + v1) + (v2 + v3);
            a1 += (v4 + v5) + (v6 + v7);
        }
        for (; k < k1; ++k) a0 += xb[(size_t)L[k] * 256];
        aggs[nl][b * 64 + lane] = a0 + a1;
    }
    // no __syncthreads: aggs[nl][b*64+*] written and read by THIS wave only
    // (per-wave lgkmcnt orders the ds_write before the ds_reads below)

    // dual-GEMM + epilogue: lane = o, this wave's (node, batch)
    {
        int o = lane;
        float bval = (o < COUT) ? bias[o] : 0.f;
        const float* xrow = xT + (size_t)n * 256 + b * 64;   // wave-uniform

        float acc0 = 0.f, acc1 = 0.f;
#pragma unroll 1
        for (int c4 = 0; c4 < 64; c4 += 4) {
            float w00 = w0s[c4 + 0][o], w01 = w0s[c4 + 1][o];
            float w02 = w0s[c4 + 2][o], w03 = w0s[c4 + 3][o];
            float w10 = w1s[c4 + 0][o], w11 = w1s[c4 + 1][o];
            float w12 = w1s[c4 + 2][o], w13 = w1s[c4 + 3][o];
            float4 xv = *reinterpret_cast<const float4*>(xrow + c4);
            float4 av = *reinterpret_cast<const float4*>(&aggs[nl][b * 64 + c4]);
            acc0 += w00 * xv.x + w01 * xv.y + w02 * xv.z + w03 * xv.w;
            acc1 += w10 * av.x + w11 * av.y + w12 * av.z + w13 * av.w;
        }

        float dg = (float)cnt;                           // true degree
        float aj = adjsum[n];                            // wave-uniform
        float rd = 1.f / ((aj == 0.f) ? 1.f : aj);
        float v = (o < COUT) ? (dg * (acc0 + bval) + acc1) * rd : aj;
        out[((size_t)(b * 64 + o)) * NNODES + n] = v;
    }
}

// ---------------- launcher --------------------------------------------------
extern "C" void kernel_launch(void* const* d_in, const int* in_sizes, int n_in,
                              void* d_out, int out_size, void* d_ws, size_t ws_size,
                              hipStream_t stream) {
    const float* x    = (const float*)d_in[0];
    const int*   adj  = (const int*)d_in[1];
    const float* vals = (const float*)d_in[2];
    const float* W    = (const float*)d_in[3];
    const float* bias = (const float*)d_in[4];
    float* out = (float*)d_out;

    const int* src = adj;
    const int* dst = adj + NEDGES;

    char* ws = (char*)d_ws;
    // layout: xT 4MB | gb 2MB | ncnt 16K | adjsum 16K
    float* xT     = (float*)(ws);
    int*   gb     = (int*)  (ws + (4 << 20));
    int*   ncnt   = (int*)  (ws + (6 << 20));
    float* adjsum = (float*)(ws + (6 << 20) + (16 << 10));

    k_zero<<<8, 1024, 0, stream>>>(ncnt, adjsum);
    k_pre <<<BATCH * (NNODES / 64), 256, 0, stream>>>(x, src, dst, vals,
                                                      xT, ncnt, gb, adjsum);
    k_main<<<NNODES / NPB, NT, 0, stream>>>(xT, gb, ncnt, adjsum, W, bias, out);
}

// Round 16
// 51.918 us; speedup vs baseline: 1.2661x; 1.2661x over previous
//
#include <hip/hip_runtime.h>

#define BATCH   4
#define CIN     64
#define NNODES  4096
#define NEDGES  131072
#define COUT    63
#define NPB     16          // nodes per k_main block
#define CAP     128         // per-node list capacity (deg ~Poisson(32), max ~70)
#define GROUPS  16          // coarse src-groups (256 nodes each)
#define GSHIFT  8           // node >> 8 = group
#define GCAP    10240       // per-group bucket capacity (avg 8192, +22 sigma)
#define LCAP    128         // per-block per-group LDS list cap (avg 64, +8 sigma)

// ---------------- k0: transpose x (b,c,n)->xT (n,b,c) + zero gcnt/adjsum ----
__global__ __launch_bounds__(256) void k_pre(const float* __restrict__ x,
                                             float* __restrict__ xT,
                                             int* __restrict__ gcnt,
                                             float* __restrict__ adjsum) {
    int blk = blockIdx.x;            // grid = B * N/64 = 256
    int tid = threadIdx.x;
    int gtid = blk * 256 + tid;
    if (gtid < NNODES) adjsum[gtid] = 0.f;
    else if (gtid < NNODES + GROUPS) gcnt[gtid - NNODES] = 0;

    __shared__ float tile[64][65];   // 65-pad: conflict-free transpose
    int b = blk >> 6;
    int n0 = (blk & 63) << 6;
    int tx = tid & 63, ty = tid >> 6;
    const float* xb = x + (size_t)b * CIN * NNODES;
#pragma unroll
    for (int c = ty; c < 64; c += 4)
        tile[c][tx] = xb[(size_t)c * NNODES + n0 + tx];     // coalesced read
    __syncthreads();
#pragma unroll
    for (int n = ty; n < 64; n += 4)                         // 256B row writes
        xT[((size_t)(n0 + n) * BATCH + b) * 64 + tx] = tile[tx][n];
}

// ---------------- k1: coarse-bin edges into 16 src-group buckets ------------
// LDS-staged: per-edge cost is an LDS atomic; only ~16 returning GLOBAL
// atomics per block (bulk reservations). adjsum scatter is fire-and-forget.
__global__ __launch_bounds__(1024) void k_coarse(const int* __restrict__ src,
                                                 const int* __restrict__ dst,
                                                 const float* __restrict__ vals,
                                                 int* __restrict__ gcnt,
                                                 int2* __restrict__ gb,
                                                 float* __restrict__ adjsum) {
    __shared__ int  lcnt[GROUPS];
    __shared__ int  gbase[GROUPS];
    __shared__ int2 lbuf[GROUPS][LCAP];      // 16KB

    int tid = threadIdx.x;
    if (tid < GROUPS) lcnt[tid] = 0;
    __syncthreads();

    int e = blockIdx.x * 1024 + tid;         // grid = NEDGES/1024 = 128 blocks
    int s = src[e], d = dst[e];
    atomicAdd(&adjsum[d], vals[e]);          // fire-and-forget float atomic
    int g = s >> GSHIFT;
    int p = atomicAdd(&lcnt[g], 1);          // LDS atomic (cheap)
    if (p < LCAP) lbuf[g][p] = make_int2(s, d);
    else {                                   // rare overflow: direct global
        int q = atomicAdd(&gcnt[g], 1);
        gb[(size_t)g * GCAP + q] = make_int2(s, d);
    }
    __syncthreads();

    if (tid < GROUPS) gbase[tid] = atomicAdd(&gcnt[tid], min(lcnt[tid], LCAP));
    __syncthreads();

    int gg = tid >> 6, lane = tid & 63;      // 16 waves <-> 16 groups
    int cg = min(lcnt[gg], LCAP);
    for (int k = lane; k < cg; k += 64)      // coalesced int2 flush
        gb[(size_t)gg * GCAP + gbase[gg] + k] = lbuf[gg][k];
}

// ---------------- k2: short scan + gather + dual-GEMM + epilogue ------------
// 256 blocks x 1024 threads; block owns 16 nodes, scans ONLY its group's
// bucket (~8K edges = 64KB; was full 2.5MB edge stream in R11).
__global__ __launch_bounds__(1024, 2) void k_main(
    const float* __restrict__ xT,
    const int2* __restrict__ gb,
    const int* __restrict__ gcnt,
    const float* __restrict__ adjsum,
    const float* __restrict__ W,
    const float* __restrict__ bias,
    float* __restrict__ out)
{
    __shared__ float w0s[64][64];        // [c][o], o=63 column zeroed (16KB)
    __shared__ float w1s[64][64];        // 16KB
    __shared__ float aggs[NPB][260];     // gathered rows, 260-pad (16.6KB)
    __shared__ int   lists[NPB][CAP];    // per-node dst lists (8KB)
    __shared__ int   lcnt[NPB];

    const int tid   = threadIdx.x;       // 0..1023
    const int nbase = blockIdx.x * NPB;
    const int g     = nbase >> GSHIFT;   // this block's coarse group
    const int wv    = tid >> 6;          // wave id = local node id
    const int lane  = tid & 63;
    const int n     = nbase + wv;

    if (tid < NPB) lcnt[tid] = 0;
    // stage W tiles (cross-wave)
    for (int i = tid; i < 64 * 64; i += 1024) {
        int c = i >> 6, o = i & 63;
        float v0 = 0.f, v1 = 0.f;
        if (o < COUT) {
            v0 = W[((size_t)o * CIN + c) * 2 + 0];
            v1 = W[((size_t)o * CIN + c) * 2 + 1];
        }
        w0s[c][o] = v0;
        w1s[c][o] = v1;
    }
    __syncthreads();                     // lcnt zeroed before scan atomics

    // scan this group's bucket; keep edges with src in [nbase, nbase+16)
    {
        const int cntg = gcnt[g];
        const int2* B = gb + (size_t)g * GCAP;
#pragma unroll 1
        for (int k = tid; k < cntg; k += 1024) {
            int2 e = B[k];
            unsigned a = (unsigned)(e.x - nbase);
            if (a < NPB) {
                int p = atomicAdd(&lcnt[a], 1);
                if (p < CAP) lists[a][p] = e.y;
            }
        }
    }
    __syncthreads();

    // gather 1KB xT rows per neighbor; wave wv <-> node n
    const int cnt = lcnt[wv];
    {
        const int k1 = min(cnt, CAP);
        const int* L = lists[wv];
        const float* xb = xT + (size_t)lane * 4;
        float4 acc = make_float4(0.f, 0.f, 0.f, 0.f);
        int k = 0;
        for (; k + 4 <= k1; k += 4) {
            int d0 = L[k], d1 = L[k + 1], d2 = L[k + 2], d3 = L[k + 3];
            float4 v0 = *reinterpret_cast<const float4*>(xb + (size_t)d0 * 256);
            float4 v1 = *reinterpret_cast<const float4*>(xb + (size_t)d1 * 256);
            float4 v2 = *reinterpret_cast<const float4*>(xb + (size_t)d2 * 256);
            float4 v3 = *reinterpret_cast<const float4*>(xb + (size_t)d3 * 256);
            acc.x += (v0.x + v1.x) + (v2.x + v3.x);
            acc.y += (v0.y + v1.y) + (v2.y + v3.y);
            acc.z += (v0.z + v1.z) + (v2.z + v3.z);
            acc.w += (v0.w + v1.w) + (v2.w + v3.w);
        }
        for (; k < k1; ++k) {
            int d = L[k];
            float4 v = *reinterpret_cast<const float4*>(xb + (size_t)d * 256);
            acc.x += v.x; acc.y += v.y; acc.z += v.z; acc.w += v.w;
        }
        *reinterpret_cast<float4*>(&aggs[wv][lane * 4]) = acc;
    }
    // no barrier: aggs[wv] is written and read by this wave only

    // dual-GEMM + epilogue: wave wv -> node n, lane = o
    {
        int o = lane;
        float bval = (o < COUT) ? bias[o] : 0.f;
        const float* xrow = xT + (size_t)n * 256;        // wave-uniform row

        float acc0[4] = {0.f, 0.f, 0.f, 0.f};            // W0 . x   per batch
        float acc1[4] = {0.f, 0.f, 0.f, 0.f};            // W1 . agg per batch

#pragma unroll 1
        for (int c4 = 0; c4 < 64; c4 += 4) {
            float w00 = w0s[c4 + 0][o], w01 = w0s[c4 + 1][o];
            float w02 = w0s[c4 + 2][o], w03 = w0s[c4 + 3][o];
            float w10 = w1s[c4 + 0][o], w11 = w1s[c4 + 1][o];
            float w12 = w1s[c4 + 2][o], w13 = w1s[c4 + 3][o];
#pragma unroll
            for (int b = 0; b < 4; ++b) {
                float4 xv = *reinterpret_cast<const float4*>(xrow + b * 64 + c4);
                float4 av = *reinterpret_cast<const float4*>(&aggs[wv][b * 64 + c4]);
                acc0[b] += w00 * xv.x + w01 * xv.y + w02 * xv.z + w03 * xv.w;
                acc1[b] += w10 * av.x + w11 * av.y + w12 * av.z + w13 * av.w;
            }
        }

        float dg = (float)cnt;                           // true degree
        float aj = adjsum[n];                            // wave-uniform
        float rd = 1.f / ((aj == 0.f) ? 1.f : aj);
#pragma unroll
        for (int b = 0; b < 4; ++b) {
            float v = (o < COUT) ? (dg * (acc0[b] + bval) + acc1[b]) * rd : aj;
            out[((size_t)(b * 64 + o)) * NNODES + n] = v;
        }
    }
}

// ---------------- launcher --------------------------------------------------
extern "C" void kernel_launch(void* const* d_in, const int* in_sizes, int n_in,
                              void* d_out, int out_size, void* d_ws, size_t ws_size,
                              hipStream_t stream) {
    const float* x    = (const float*)d_in[0];
    const int*   adj  = (const int*)d_in[1];
    const float* vals = (const float*)d_in[2];
    const float* W    = (const float*)d_in[3];
    const float* bias = (const float*)d_in[4];
    float* out = (float*)d_out;

    const int* src = adj;
    const int* dst = adj + NEDGES;

    char* ws = (char*)d_ws;
    // layout: xT 4MB | gb 1.25MB | gcnt 64B.. | adjsum 16K
    float* xT     = (float*)(ws);
    int2*  gb     = (int2*) (ws + (4 << 20));
    int*   gcnt   = (int*)  (ws + (6 << 20));
    float* adjsum = (float*)(ws + (6 << 20) + (4 << 10));

    k_pre   <<<BATCH * (NNODES / 64), 256, 0, stream>>>(x, xT, gcnt, adjsum);
    k_coarse<<<NEDGES / 1024, 1024, 0, stream>>>(src, dst, vals, gcnt, gb, adjsum);
    k_main  <<<NNODES / NPB, 1024, 0, stream>>>(xT, gb, gcnt, adjsum, W, bias, out);
}

// Round 17
// 46.471 us; speedup vs baseline: 1.4145x; 1.1172x over previous
//
#include <hip/hip_runtime.h>

#define BATCH   4
#define CIN     64
#define NNODES  4096
#define NEDGES  131072
#define COUT    63
#define NPB     16          // nodes per k_main block
#define CAP     128         // per-node list capacity (deg ~Poisson(32))
#define GROUPS  16          // coarse groups (256 nodes each)
#define GSHIFT  8           // node >> 8 = group
#define PBLK    128         // binning blocks (1024 edges each)
#define SEGCAP  128         // slots per (group, segment); mean fill 64
#define SEGSH   7

// ---------------- k_prep: transpose + atomic-free dual binning --------------
// 256 blocks x 1024 threads. All blocks transpose x (b,c,n)->xT (n,b,c);
// blocks 0..127 additionally bin 1024 edges into per-(group,block) SEGMENTS:
//   sgb[g][blk][k] = (src,dst)      for src-group g   (k_main neighbor lists)
//   dgb[g][blk][k] = (dst,val)      for dst-group g   (k_main denominators)
// Counts are rewritten every call -> no zero-init, no global atomics,
// graph-replay safe by construction.
__global__ __launch_bounds__(1024) void k_prep(
    const float* __restrict__ x,
    const int* __restrict__ src,
    const int* __restrict__ dst,
    const float* __restrict__ vals,
    float* __restrict__ xT,
    int2* __restrict__ sgb,
    int2* __restrict__ dgb,
    int* __restrict__ scnt,
    int* __restrict__ dcnt)
{
    __shared__ float tile[64][65];           // conflict-free transpose (16.6KB)
    __shared__ int2  sbuf[GROUPS][SEGCAP];   // 16KB
    __shared__ int2  dbuf[GROUPS][SEGCAP];   // 16KB
    __shared__ int   slcnt[GROUPS], dlcnt[GROUPS];

    const int blk = blockIdx.x;
    const int tid = threadIdx.x;
    const bool binner = blk < PBLK;

    if (binner && tid < GROUPS) { slcnt[tid] = 0; dlcnt[tid] = 0; }
    __syncthreads();

    if (binner) {                            // 1 edge per thread, coalesced
        int e = blk * 1024 + tid;
        int s = src[e], d = dst[e];
        float v = vals[e];
        int gs = s >> GSHIFT;
        int p = atomicAdd(&slcnt[gs], 1);    // LDS atomic
        if (p < SEGCAP) sbuf[gs][p] = make_int2(s, d);
        int gd = d >> GSHIFT;
        int q = atomicAdd(&dlcnt[gd], 1);
        if (q < SEGCAP) dbuf[gd][q] = make_int2(d, __float_as_int(v));
    }

    // transpose (all blocks): block = (batch, 64-node tile)
    int b = blk >> 6;
    int n0 = (blk & 63) << 6;
    int tx = tid & 63, ty = tid >> 6;        // ty 0..15
    const float* xb = x + (size_t)b * CIN * NNODES;
#pragma unroll
    for (int c = ty; c < 64; c += 16)
        tile[c][tx] = xb[(size_t)c * NNODES + n0 + tx];     // coalesced read
    __syncthreads();                         // also orders the LDS bin atomics
#pragma unroll
    for (int n = ty; n < 64; n += 16)                        // 256B row writes
        xT[((size_t)(n0 + n) * BATCH + b) * 64 + tx] = tile[tx][n];

    // flush segments: wave g flushes group g (coalesced int2 stores)
    if (binner) {
        int g = tid >> 6, lane = tid & 63;   // 16 waves <-> 16 groups
        int sc = min(slcnt[g], SEGCAP);
        int dc = min(dlcnt[g], SEGCAP);
        size_t base = ((size_t)(g * PBLK + blk)) << SEGSH;
        for (int k = lane; k < sc; k += 64) sgb[base + k] = sbuf[g][k];
        for (int k = lane; k < dc; k += 64) dgb[base + k] = dbuf[g][k];
        if (lane == 0) { scnt[g * PBLK + blk] = sc; dcnt[g * PBLK + blk] = dc; }
    }
}

// ---------------- k_main: segment scan + gather + dual-GEMM + epilogue ------
// 256 blocks x 1024 threads; block owns nodes [blk*16, blk*16+16).
// Reads only its group's segments (count-gated). All state block-local.
__global__ __launch_bounds__(1024, 2) void k_main(
    const float* __restrict__ xT,
    const int2* __restrict__ sgb,
    const int2* __restrict__ dgb,
    const int* __restrict__ scnt,
    const int* __restrict__ dcnt,
    const float* __restrict__ W,
    const float* __restrict__ bias,
    float* __restrict__ out)
{
    __shared__ float w0s[64][64];        // [c][o], o=63 column zeroed (16KB)
    __shared__ float w1s[64][64];        // 16KB
    __shared__ float aggs[NPB][260];     // gathered rows, 260-pad (16.6KB)
    __shared__ int   lists[NPB][CAP];    // per-node dst lists (8KB)
    __shared__ int   lcnt[NPB];
    __shared__ float adjs[NPB];
    __shared__ int   scn[PBLK], dcn[PBLK];   // 1KB

    const int tid   = threadIdx.x;       // 0..1023
    const int nbase = blockIdx.x * NPB;
    const int g     = blockIdx.x >> 4;   // this block's coarse group
    const int wv    = tid >> 6;          // wave id = local node id
    const int lane  = tid & 63;
    const int n     = nbase + wv;

    if (tid < NPB) { lcnt[tid] = 0; adjs[tid] = 0.f; }
    if (tid < PBLK) {
        scn[tid] = scnt[g * PBLK + tid];
        dcn[tid] = dcnt[g * PBLK + tid];
    }
    // stage W tiles (cross-wave)
    for (int i = tid; i < 64 * 64; i += 1024) {
        int c = i >> 6, o = i & 63;
        float v0 = 0.f, v1 = 0.f;
        if (o < COUT) {
            v0 = W[((size_t)o * CIN + c) * 2 + 0];
            v1 = W[((size_t)o * CIN + c) * 2 + 1];
        }
        w0s[c][o] = v0;
        w1s[c][o] = v1;
    }
    __syncthreads();

    // scan src segments: keep edges with src in [nbase, nbase+16)
#pragma unroll 1
    for (int i = tid; i < PBLK * SEGCAP; i += 1024) {
        int seg = i >> SEGSH, k = i & (SEGCAP - 1);
        if (k < scn[seg]) {
            int2 e = sgb[(((size_t)g * PBLK + seg) << SEGSH) + k];
            unsigned a = (unsigned)(e.x - nbase);
            if (a < NPB) {
                int p = atomicAdd(&lcnt[a], 1);
                if (p < CAP) lists[a][p] = e.y;
            }
        }
    }
    // scan dst segments: accumulate denominators for own nodes
#pragma unroll 1
    for (int i = tid; i < PBLK * SEGCAP; i += 1024) {
        int seg = i >> SEGSH, k = i & (SEGCAP - 1);
        if (k < dcn[seg]) {
            int2 e = dgb[(((size_t)g * PBLK + seg) << SEGSH) + k];
            unsigned a = (unsigned)(e.x - nbase);
            if (a < NPB) atomicAdd(&adjs[a], __int_as_float(e.y));
        }
    }
    __syncthreads();

    // gather 1KB xT rows per neighbor; wave wv <-> node n
    const int cnt = lcnt[wv];
    {
        const int k1 = min(cnt, CAP);
        const int* L = lists[wv];
        const float* xb = xT + (size_t)lane * 4;
        float4 acc = make_float4(0.f, 0.f, 0.f, 0.f);
        int k = 0;
        for (; k + 4 <= k1; k += 4) {
            int d0 = L[k], d1 = L[k + 1], d2 = L[k + 2], d3 = L[k + 3];
            float4 v0 = *reinterpret_cast<const float4*>(xb + (size_t)d0 * 256);
            float4 v1 = *reinterpret_cast<const float4*>(xb + (size_t)d1 * 256);
            float4 v2 = *reinterpret_cast<const float4*>(xb + (size_t)d2 * 256);
            float4 v3 = *reinterpret_cast<const float4*>(xb + (size_t)d3 * 256);
            acc.x += (v0.x + v1.x) + (v2.x + v3.x);
            acc.y += (v0.y + v1.y) + (v2.y + v3.y);
            acc.z += (v0.z + v1.z) + (v2.z + v3.z);
            acc.w += (v0.w + v1.w) + (v2.w + v3.w);
        }
        for (; k < k1; ++k) {
            int d = L[k];
            float4 v = *reinterpret_cast<const float4*>(xb + (size_t)d * 256);
            acc.x += v.x; acc.y += v.y; acc.z += v.z; acc.w += v.w;
        }
        *reinterpret_cast<float4*>(&aggs[wv][lane * 4]) = acc;
    }
    // no barrier: aggs[wv] is written and read by this wave only

    // dual-GEMM + epilogue: wave wv -> node n, lane = o
    {
        int o = lane;
        float bval = (o < COUT) ? bias[o] : 0.f;
        const float* xrow = xT + (size_t)n * 256;        // wave-uniform row

        float acc0[4] = {0.f, 0.f, 0.f, 0.f};            // W0 . x   per batch
        float acc1[4] = {0.f, 0.f, 0.f, 0.f};            // W1 . agg per batch

#pragma unroll 1
        for (int c4 = 0; c4 < 64; c4 += 4) {
            float w00 = w0s[c4 + 0][o], w01 = w0s[c4 + 1][o];
            float w02 = w0s[c4 + 2][o], w03 = w0s[c4 + 3][o];
            float w10 = w1s[c4 + 0][o], w11 = w1s[c4 + 1][o];
            float w12 = w1s[c4 + 2][o], w13 = w1s[c4 + 3][o];
#pragma unroll
            for (int b = 0; b < 4; ++b) {
                float4 xv = *reinterpret_cast<const float4*>(xrow + b * 64 + c4);
                float4 av = *reinterpret_cast<const float4*>(&aggs[wv][b * 64 + c4]);
                acc0[b] += w00 * xv.x + w01 * xv.y + w02 * xv.z + w03 * xv.w;
                acc1[b] += w10 * av.x + w11 * av.y + w12 * av.z + w13 * av.w;
            }
        }

        float dg = (float)cnt;                           // true degree
        float aj = adjs[wv];                             // block-local denom
        float rd = 1.f / ((aj == 0.f) ? 1.f : aj);
#pragma unroll
        for (int b = 0; b < 4; ++b) {
            float v = (o < COUT) ? (dg * (acc0[b] + bval) + acc1[b]) * rd : aj;
            out[((size_t)(b * 64 + o)) * NNODES + n] = v;   // lines merge per block
        }
    }
}

// ---------------- launcher --------------------------------------------------
extern "C" void kernel_launch(void* const* d_in, const int* in_sizes, int n_in,
                              void* d_out, int out_size, void* d_ws, size_t ws_size,
                              hipStream_t stream) {
    const float* x    = (const float*)d_in[0];
    const int*   adj  = (const int*)d_in[1];
    const float* vals = (const float*)d_in[2];
    const float* W    = (const float*)d_in[3];
    const float* bias = (const float*)d_in[4];
    float* out = (float*)d_out;

    const int* src = adj;
    const int* dst = adj + NEDGES;

    char* ws = (char*)d_ws;
    // layout: xT 4MB | sgb 2MB | dgb 2MB | scnt 8K | dcnt 8K   (8.27MB total)
    float* xT   = (float*)(ws);
    int2*  sgb  = (int2*) (ws + (4 << 20));
    int2*  dgb  = (int2*) (ws + (6 << 20));
    int*   scnt = (int*)  (ws + (8 << 20));
    int*   dcnt = (int*)  (ws + (8 << 20) + (8 << 10));

    k_prep<<<BATCH * (NNODES / 64), 1024, 0, stream>>>(x, src, dst, vals,
                                                       xT, sgb, dgb, scnt, dcnt);
    k_main<<<NNODES / NPB, 1024, 0, stream>>>(xT, sgb, dgb, scnt, dcnt,
                                              W, bias, out);
}

// Round 18
// 44.293 us; speedup vs baseline: 1.4841x; 1.0492x over previous
//
#include <hip/hip_runtime.h>

#define BATCH   4
#define CIN     64
#define NNODES  4096
#define NEDGES  131072
#define COUT    63
#define NPB     16          // nodes per k_main block
#define CAP     128         // per-node list capacity (deg ~Poisson(32))
#define GROUPS  16          // coarse groups (256 nodes each)
#define GSHIFT  8           // node >> 8 = group
#define PBLK    128         // binning blocks (1024 edges each)
#define SEGCAP  128         // slots per (group, segment); mean fill 64
#define SEGSH   7

// ---------------- k_prep: transpose + atomic-free dual binning --------------
// (unchanged from R17 — proven)
__global__ __launch_bounds__(1024) void k_prep(
    const float* __restrict__ x,
    const int* __restrict__ src,
    const int* __restrict__ dst,
    const float* __restrict__ vals,
    float* __restrict__ xT,
    int2* __restrict__ sgb,
    int2* __restrict__ dgb,
    int* __restrict__ scnt,
    int* __restrict__ dcnt)
{
    __shared__ float tile[64][65];           // conflict-free transpose (16.6KB)
    __shared__ int2  sbuf[GROUPS][SEGCAP];   // 16KB
    __shared__ int2  dbuf[GROUPS][SEGCAP];   // 16KB
    __shared__ int   slcnt[GROUPS], dlcnt[GROUPS];

    const int blk = blockIdx.x;
    const int tid = threadIdx.x;
    const bool binner = blk < PBLK;

    if (binner && tid < GROUPS) { slcnt[tid] = 0; dlcnt[tid] = 0; }
    __syncthreads();

    if (binner) {                            // 1 edge per thread, coalesced
        int e = blk * 1024 + tid;
        int s = src[e], d = dst[e];
        float v = vals[e];
        int gs = s >> GSHIFT;
        int p = atomicAdd(&slcnt[gs], 1);    // LDS atomic
        if (p < SEGCAP) sbuf[gs][p] = make_int2(s, d);
        int gd = d >> GSHIFT;
        int q = atomicAdd(&dlcnt[gd], 1);
        if (q < SEGCAP) dbuf[gd][q] = make_int2(d, __float_as_int(v));
    }

    // transpose (all blocks): block = (batch, 64-node tile)
    int b = blk >> 6;
    int n0 = (blk & 63) << 6;
    int tx = tid & 63, ty = tid >> 6;        // ty 0..15
    const float* xb = x + (size_t)b * CIN * NNODES;
#pragma unroll
    for (int c = ty; c < 64; c += 16)
        tile[c][tx] = xb[(size_t)c * NNODES + n0 + tx];     // coalesced read
    __syncthreads();                         // also orders the LDS bin atomics
#pragma unroll
    for (int n = ty; n < 64; n += 16)                        // 256B row writes
        xT[((size_t)(n0 + n) * BATCH + b) * 64 + tx] = tile[tx][n];

    // flush segments: wave g flushes group g (coalesced int2 stores)
    if (binner) {
        int g = tid >> 6, lane = tid & 63;   // 16 waves <-> 16 groups
        int sc = min(slcnt[g], SEGCAP);
        int dc = min(dlcnt[g], SEGCAP);
        size_t base = ((size_t)(g * PBLK + blk)) << SEGSH;
        for (int k = lane; k < sc; k += 64) sgb[base + k] = sbuf[g][k];
        for (int k = lane; k < dc; k += 64) dgb[base + k] = dbuf[g][k];
        if (lane == 0) { scnt[g * PBLK + blk] = sc; dcnt[g * PBLK + blk] = dc; }
    }
}

// ---------------- k_main: segment scan + gather + dual-GEMM + epilogue ------
// R18 changes vs R17 (both fix 64-line/instruction address scatter):
//  1. W staged via coalesced float2 loads (was 512B/lane stride = 64 lines
//     per wave-load); w0s/w1s padded [64][65] so the LDS scatter-write is
//     conflict-free; GEMM broadcast reads stay conflict-free.
//  2. Output staged in LDS res[4][64][17] (union over dead `lists`), then
//     flushed with lanes spanning n: 4 full 64B lines per store instruction
//     (was 64 scattered lines per store).
//  3. Gather unrolled 8-deep (more loads in flight per wave).
__global__ __launch_bounds__(1024, 2) void k_main(
    const float* __restrict__ xT,
    const int2* __restrict__ sgb,
    const int2* __restrict__ dgb,
    const int* __restrict__ scnt,
    const int* __restrict__ dcnt,
    const float* __restrict__ W,
    const float* __restrict__ bias,
    float* __restrict__ out)
{
    __shared__ float w0s[64][65];        // [c][o], padded; o=63 col zeroed
    __shared__ float w1s[64][65];
    __shared__ float aggs[NPB][260];     // gathered rows, 260-pad (16.6KB)
    __shared__ union U {
        int   lists[NPB][CAP];           // 8KB   (scan+gather phases)
        float res[BATCH][64][17];        // 17.4KB (epilogue staging)
    } u;
    __shared__ int   lcnt[NPB];
    __shared__ float adjs[NPB];
    __shared__ int   scn[PBLK], dcn[PBLK];   // 1KB

    const int tid   = threadIdx.x;       // 0..1023
    const int nbase = blockIdx.x * NPB;
    const int g     = blockIdx.x >> 4;   // this block's coarse group
    const int wv    = tid >> 6;          // wave id = local node id
    const int lane  = tid & 63;
    const int n     = nbase + wv;

    if (tid < NPB) { lcnt[tid] = 0; adjs[tid] = 0.f; }
    if (tid < PBLK) {
        scn[tid] = scnt[g * PBLK + tid];
        dcn[tid] = dcnt[g * PBLK + tid];
    }
    // stage W: coalesced float2 (lane i -> W2[i]), scatter to padded LDS
    {
        const float2* W2 = reinterpret_cast<const float2*>(W);
#pragma unroll
        for (int i = tid; i < COUT * CIN; i += 1024) {   // 4032 float2
            float2 v = W2[i];
            int o = i >> 6, c = i & 63;
            w0s[c][o] = v.x;
            w1s[c][o] = v.y;
        }
        if (tid < 64) { w0s[tid][63] = 0.f; w1s[tid][63] = 0.f; }
    }
    __syncthreads();

    // scan src segments: keep edges with src in [nbase, nbase+16)
#pragma unroll 1
    for (int i = tid; i < PBLK * SEGCAP; i += 1024) {
        int seg = i >> SEGSH, k = i & (SEGCAP - 1);
        if (k < scn[seg]) {
            int2 e = sgb[(((size_t)g * PBLK + seg) << SEGSH) + k];
            unsigned a = (unsigned)(e.x - nbase);
            if (a < NPB) {
                int p = atomicAdd(&lcnt[a], 1);
                if (p < CAP) u.lists[a][p] = e.y;
            }
        }
    }
    // scan dst segments: accumulate denominators for own nodes
#pragma unroll 1
    for (int i = tid; i < PBLK * SEGCAP; i += 1024) {
        int seg = i >> SEGSH, k = i & (SEGCAP - 1);
        if (k < dcn[seg]) {
            int2 e = dgb[(((size_t)g * PBLK + seg) << SEGSH) + k];
            unsigned a = (unsigned)(e.x - nbase);
            if (a < NPB) atomicAdd(&adjs[a], __int_as_float(e.y));
        }
    }
    __syncthreads();

    // gather 1KB xT rows per neighbor; wave wv <-> node n; 8 rows in flight
    const int cnt = lcnt[wv];
    {
        const int k1 = min(cnt, CAP);
        const int* L = u.lists[wv];
        const float* xb = xT + (size_t)lane * 4;
        float4 accA = make_float4(0.f, 0.f, 0.f, 0.f);
        float4 accB = make_float4(0.f, 0.f, 0.f, 0.f);
        int k = 0;
        for (; k + 8 <= k1; k += 8) {
            float4 v0 = *reinterpret_cast<const float4*>(xb + (size_t)L[k + 0] * 256);
            float4 v1 = *reinterpret_cast<const float4*>(xb + (size_t)L[k + 1] * 256);
            float4 v2 = *reinterpret_cast<const float4*>(xb + (size_t)L[k + 2] * 256);
            float4 v3 = *reinterpret_cast<const float4*>(xb + (size_t)L[k + 3] * 256);
            float4 v4 = *reinterpret_cast<const float4*>(xb + (size_t)L[k + 4] * 256);
            float4 v5 = *reinterpret_cast<const float4*>(xb + (size_t)L[k + 5] * 256);
            float4 v6 = *reinterpret_cast<const float4*>(xb + (size_t)L[k + 6] * 256);
            float4 v7 = *reinterpret_cast<const float4*>(xb + (size_t)L[k + 7] * 256);
            accA.x += (v0.x + v1.x) + (v2.x + v3.x);
            accA.y += (v0.y + v1.y) + (v2.y + v3.y);
            accA.z += (v0.z + v1.z) + (v2.z + v3.z);
            accA.w += (v0.w + v1.w) + (v2.w + v3.w);
            accB.x += (v4.x + v5.x) + (v6.x + v7.x);
            accB.y += (v4.y + v5.y) + (v6.y + v7.y);
            accB.z += (v4.z + v5.z) + (v6.z + v7.z);
            accB.w += (v4.w + v5.w) + (v6.w + v7.w);
        }
        for (; k < k1; ++k) {
            float4 v = *reinterpret_cast<const float4*>(xb + (size_t)L[k] * 256);
            accA.x += v.x; accA.y += v.y; accA.z += v.z; accA.w += v.w;
        }
        accA.x += accB.x; accA.y += accB.y; accA.z += accB.z; accA.w += accB.w;
        *reinterpret_cast<float4*>(&aggs[wv][lane * 4]) = accA;
    }
    __syncthreads();                     // lists dead beyond this point

    // dual-GEMM: wave wv -> node n, lane = o; stage result in u.res
    {
        int o = lane;
        float bval = (o < COUT) ? bias[o] : 0.f;
        const float* xrow = xT + (size_t)n * 256;        // wave-uniform row

        float acc0[4] = {0.f, 0.f, 0.f, 0.f};            // W0 . x   per batch
        float acc1[4] = {0.f, 0.f, 0.f, 0.f};            // W1 . agg per batch

#pragma unroll 1
        for (int c4 = 0; c4 < 64; c4 += 4) {
            float w00 = w0s[c4 + 0][o], w01 = w0s[c4 + 1][o];
            float w02 = w0s[c4 + 2][o], w03 = w0s[c4 + 3][o];
            float w10 = w1s[c4 + 0][o], w11 = w1s[c4 + 1][o];
            float w12 = w1s[c4 + 2][o], w13 = w1s[c4 + 3][o];
#pragma unroll
            for (int b = 0; b < 4; ++b) {
                float4 xv = *reinterpret_cast<const float4*>(xrow + b * 64 + c4);
                float4 av = *reinterpret_cast<const float4*>(&aggs[wv][b * 64 + c4]);
                acc0[b] += w00 * xv.x + w01 * xv.y + w02 * xv.z + w03 * xv.w;
                acc1[b] += w10 * av.x + w11 * av.y + w12 * av.z + w13 * av.w;
            }
        }

        float dg = (float)cnt;                           // true degree
        float aj = adjs[wv];                             // block-local denom
        float rd = 1.f / ((aj == 0.f) ? 1.f : aj);
#pragma unroll
        for (int b = 0; b < 4; ++b) {
            float v = (o < COUT) ? (dg * (acc0[b] + bval) + acc1[b]) * rd : aj;
            u.res[b][o][wv] = v;         // stride 17: conflict-free
        }
    }
    __syncthreads();

    // coalesced flush: lanes span n -> 4 full 64B lines per store instruction
#pragma unroll
    for (int i = tid; i < BATCH * 64 * NPB; i += 1024) {  // 4096
        int b = i >> 10, o = (i >> 4) & 63, nl = i & 15;
        out[((size_t)(b * 64 + o)) * NNODES + nbase + nl] = u.res[b][o][nl];
    }
}

// ---------------- launcher --------------------------------------------------
extern "C" void kernel_launch(void* const* d_in, const int* in_sizes, int n_in,
                              void* d_out, int out_size, void* d_ws, size_t ws_size,
                              hipStream_t stream) {
    const float* x    = (const float*)d_in[0];
    const int*   adj  = (const int*)d_in[1];
    const float* vals = (const float*)d_in[2];
    const float* W    = (const float*)d_in[3];
    const float* bias = (const float*)d_in[4];
    float* out = (float*)d_out;

    const int* src = adj;
    const int* dst = adj + NEDGES;

    char* ws = (char*)d_ws;
    // layout: xT 4MB | sgb 2MB | dgb 2MB | scnt 8K | dcnt 8K   (8.27MB total)
    float* xT   = (float*)(ws);
    int2*  sgb  = (int2*) (ws + (4 << 20));
    int2*  dgb  = (int2*) (ws + (6 << 20));
    int*   scnt = (int*)  (ws + (8 << 20));
    int*   dcnt = (int*)  (ws + (8 << 20) + (8 << 10));

    k_prep<<<BATCH * (NNODES / 64), 1024, 0, stream>>>(x, src, dst, vals,
                                                       xT, sgb, dgb, scnt, dcnt);
    k_main<<<NNODES / NPB, 1024, 0, stream>>>(xT, sgb, dgb, scnt, dcnt,
                                              W, bias, out);
}

// Round 19
// 39.075 us; speedup vs baseline: 1.6823x; 1.1335x over previous
//
#include <hip/hip_runtime.h>

#define BATCH   4
#define CIN     64
#define NNODES  4096
#define NEDGES  131072
#define COUT    63
#define NPB     16          // nodes per k_main block
#define CAP     128         // per-node list capacity (deg ~Poisson(32))
#define GROUPS  256         // fine groups: ONE group per k_main block
#define GSHIFT  4           // node >> 4 = group
#define PBLK    256         // binning blocks (512 edges each)
#define SEGCAP  16          // slots per (group, segment); mean fill 2
#define SEGSH   4

// ---------------- k_prep: transpose + atomic-free fine binning --------------
// 256 blocks x 1024 threads. Every block: bins 512 edges (two LDS passes,
// reusing one buffer) AND transposes one (batch, 64-node) tile of x.
// Segments are per-(group, block) fixed slots: counts rewritten every call,
// no zero-init, no global atomics -> graph-replay safe.
__global__ __launch_bounds__(1024) void k_prep(
    const float* __restrict__ x,
    const int* __restrict__ src,
    const int* __restrict__ dst,
    const float* __restrict__ vals,
    float* __restrict__ xT,
    int* __restrict__ sgb,
    int2* __restrict__ dgb,
    int* __restrict__ scnt,
    int* __restrict__ dcnt)
{
    __shared__ float tile[64][65];           // conflict-free transpose (16.6KB)
    __shared__ union BB {
        int  s[GROUPS][SEGCAP];              // 16KB (src pass)
        int2 d[GROUPS][SEGCAP];              // 32KB (dst pass)
    } bb;
    __shared__ int bcnt[GROUPS];             // 1KB

    const int blk = blockIdx.x;
    const int tid = threadIdx.x;
    const int w = tid >> 6, lane = tid & 63;

    // this block's 512 edges (tid < 512)
    int s_ = 0, d_ = 0; float v_ = 0.f;
    const bool hasE = tid < 512;
    if (hasE) {
        int e = blk * 512 + tid;
        s_ = src[e]; d_ = dst[e]; v_ = vals[e];
    }

    // ---- pass 1: bin by src-group; entry packs (local_src<<12 | dst) ------
    if (tid < GROUPS) bcnt[tid] = 0;
    __syncthreads();
    if (hasE) {
        int g = s_ >> GSHIFT;
        int p = atomicAdd(&bcnt[g], 1);
        if (p < SEGCAP) bb.s[g][p] = ((s_ & (NPB - 1)) << 12) | d_;
    }
    __syncthreads();
#pragma unroll
    for (int it = 0; it < GROUPS / 16; ++it) {       // wave w -> 16 groups
        int g = w * 16 + it;
        int sc = min(bcnt[g], SEGCAP);
        if (lane < sc) sgb[((size_t)(g * PBLK + blk) << SEGSH) + lane] = bb.s[g][lane];
        if (lane == 0) scnt[g * PBLK + blk] = sc;
    }
    __syncthreads();

    // ---- pass 2: bin by dst-group; entry = (local_dst, val_bits) -----------
    if (tid < GROUPS) bcnt[tid] = 0;
    __syncthreads();
    if (hasE) {
        int g = d_ >> GSHIFT;
        int q = atomicAdd(&bcnt[g], 1);
        if (q < SEGCAP) bb.d[g][q] = make_int2(d_ & (NPB - 1), __float_as_int(v_));
    }
    __syncthreads();
#pragma unroll
    for (int it = 0; it < GROUPS / 16; ++it) {
        int g = w * 16 + it;
        int dc = min(bcnt[g], SEGCAP);
        if (lane < dc) dgb[((size_t)(g * PBLK + blk) << SEGSH) + lane] = bb.d[g][lane];
        if (lane == 0) dcnt[g * PBLK + blk] = dc;
    }

    // ---- transpose (all blocks): block = (batch, 64-node tile) -------------
    int b = blk >> 6;
    int n0 = (blk & 63) << 6;
    int tx = tid & 63, ty = tid >> 6;        // ty 0..15
    const float* xb = x + (size_t)b * CIN * NNODES;
#pragma unroll
    for (int c = ty; c < 64; c += 16)
        tile[c][tx] = xb[(size_t)c * NNODES + n0 + tx];     // coalesced read
    __syncthreads();
#pragma unroll
    for (int n = ty; n < 64; n += 16)                        // 256B row writes
        xT[((size_t)(n0 + n) * BATCH + b) * 64 + tx] = tile[tx][n];
}

// ---------------- k_main: own-segment scan + gather + dual-GEMM + epilogue --
// 256 blocks x 1024 threads; block g owns nodes [g*16, g*16+16) and reads
// ONLY its own group's segments (48KB; was 256KB shared 16-ways in R18).
__global__ __launch_bounds__(1024, 2) void k_main(
    const float* __restrict__ xT,
    const int* __restrict__ sgb,
    const int2* __restrict__ dgb,
    const int* __restrict__ scnt,
    const int* __restrict__ dcnt,
    const float* __restrict__ W,
    const float* __restrict__ bias,
    float* __restrict__ out)
{
    __shared__ float w0s[64][65];        // [c][o], padded; o=63 col zeroed
    __shared__ float w1s[64][65];
    __shared__ float aggs[NPB][260];     // gathered rows, 260-pad (16.6KB)
    __shared__ union U {
        int   lists[NPB][CAP];           // 8KB   (scan+gather phases)
        float res[BATCH][64][17];        // 17.4KB (epilogue staging)
    } u;
    __shared__ int   lcnt[NPB];
    __shared__ float adjs[NPB];
    __shared__ int   scn[PBLK], dcn[PBLK];   // 2KB

    const int tid   = threadIdx.x;       // 0..1023
    const int g     = blockIdx.x;        // group == block
    const int nbase = g * NPB;
    const int wv    = tid >> 6;          // wave id = local node id
    const int lane  = tid & 63;
    const int n     = nbase + wv;

    if (tid < NPB) { lcnt[tid] = 0; adjs[tid] = 0.f; }
    if (tid < PBLK) {
        scn[tid] = scnt[g * PBLK + tid];     // coalesced 1KB
        dcn[tid] = dcnt[g * PBLK + tid];
    }
    // stage W: coalesced float2 loads, scatter to padded LDS
    {
        const float2* W2 = reinterpret_cast<const float2*>(W);
#pragma unroll
        for (int i = tid; i < COUT * CIN; i += 1024) {   // 4032 float2
            float2 v = W2[i];
            int o = i >> 6, c = i & 63;
            w0s[c][o] = v.x;
            w1s[c][o] = v.y;
        }
        if (tid < 64) { w0s[tid][63] = 0.f; w1s[tid][63] = 0.f; }
    }
    __syncthreads();

    // scan own src segments (4096 gated slots = 16KB)
#pragma unroll 1
    for (int i = tid; i < PBLK * SEGCAP; i += 1024) {
        int seg = i >> SEGSH, k = i & (SEGCAP - 1);
        if (k < scn[seg]) {
            int e = sgb[((size_t)g * PBLK << SEGSH) + i];
            int a = e >> 12;                 // local src 0..15
            int p = atomicAdd(&lcnt[a], 1);
            if (p < CAP) u.lists[a][p] = e & 0xFFF;
        }
    }
    // scan own dst segments (4096 gated slots = 32KB)
#pragma unroll 1
    for (int i = tid; i < PBLK * SEGCAP; i += 1024) {
        int seg = i >> SEGSH, k = i & (SEGCAP - 1);
        if (k < dcn[seg]) {
            int2 e = dgb[((size_t)g * PBLK << SEGSH) + i];
            atomicAdd(&adjs[e.x], __int_as_float(e.y));
        }
    }
    __syncthreads();

    // gather 1KB xT rows per neighbor; wave wv <-> node n; 8 rows in flight
    const int cnt = lcnt[wv];
    {
        const int k1 = min(cnt, CAP);
        const int* L = u.lists[wv];
        const float* xb = xT + (size_t)lane * 4;
        float4 accA = make_float4(0.f, 0.f, 0.f, 0.f);
        float4 accB = make_float4(0.f, 0.f, 0.f, 0.f);
        int k = 0;
        for (; k + 8 <= k1; k += 8) {
            float4 v0 = *reinterpret_cast<const float4*>(xb + (size_t)L[k + 0] * 256);
            float4 v1 = *reinterpret_cast<const float4*>(xb + (size_t)L[k + 1] * 256);
            float4 v2 = *reinterpret_cast<const float4*>(xb + (size_t)L[k + 2] * 256);
            float4 v3 = *reinterpret_cast<const float4*>(xb + (size_t)L[k + 3] * 256);
            float4 v4 = *reinterpret_cast<const float4*>(xb + (size_t)L[k + 4] * 256);
            float4 v5 = *reinterpret_cast<const float4*>(xb + (size_t)L[k + 5] * 256);
            float4 v6 = *reinterpret_cast<const float4*>(xb + (size_t)L[k + 6] * 256);
            float4 v7 = *reinterpret_cast<const float4*>(xb + (size_t)L[k + 7] * 256);
            accA.x += (v0.x + v1.x) + (v2.x + v3.x);
            accA.y += (v0.y + v1.y) + (v2.y + v3.y);
            accA.z += (v0.z + v1.z) + (v2.z + v3.z);
            accA.w += (v0.w + v1.w) + (v2.w + v3.w);
            accB.x += (v4.x + v5.x) + (v6.x + v7.x);
            accB.y += (v4.y + v5.y) + (v6.y + v7.y);
            accB.z += (v4.z + v5.z) + (v6.z + v7.z);
            accB.w += (v4.w + v5.w) + (v6.w + v7.w);
        }
        for (; k < k1; ++k) {
            float4 v = *reinterpret_cast<const float4*>(xb + (size_t)L[k] * 256);
            accA.x += v.x; accA.y += v.y; accA.z += v.z; accA.w += v.w;
        }
        accA.x += accB.x; accA.y += accB.y; accA.z += accB.z; accA.w += accB.w;
        *reinterpret_cast<float4*>(&aggs[wv][lane * 4]) = accA;
    }
    __syncthreads();                     // lists dead beyond this point

    // dual-GEMM: wave wv -> node n, lane = o; stage result in u.res
    {
        int o = lane;
        float bval = (o < COUT) ? bias[o] : 0.f;
        const float* xrow = xT + (size_t)n * 256;        // wave-uniform row

        float acc0[4] = {0.f, 0.f, 0.f, 0.f};            // W0 . x   per batch
        float acc1[4] = {0.f, 0.f, 0.f, 0.f};            // W1 . agg per batch

#pragma unroll 1
        for (int c4 = 0; c4 < 64; c4 += 4) {
            float w00 = w0s[c4 + 0][o], w01 = w0s[c4 + 1][o];
            float w02 = w0s[c4 + 2][o], w03 = w0s[c4 + 3][o];
            float w10 = w1s[c4 + 0][o], w11 = w1s[c4 + 1][o];
            float w12 = w1s[c4 + 2][o], w13 = w1s[c4 + 3][o];
#pragma unroll
            for (int b = 0; b < 4; ++b) {
                float4 xv = *reinterpret_cast<const float4*>(xrow + b * 64 + c4);
                float4 av = *reinterpret_cast<const float4*>(&aggs[wv][b * 64 + c4]);
                acc0[b] += w00 * xv.x + w01 * xv.y + w02 * xv.z + w03 * xv.w;
                acc1[b] += w10 * av.x + w11 * av.y + w12 * av.z + w13 * av.w;
            }
        }

        float dg = (float)cnt;                           // true degree
        float aj = adjs[wv];                             // block-local denom
        float rd = 1.f / ((aj == 0.f) ? 1.f : aj);
#pragma unroll
        for (int b = 0; b < 4; ++b) {
            float v = (o < COUT) ? (dg * (acc0[b] + bval) + acc1[b]) * rd : aj;
            u.res[b][o][wv] = v;         // stride 17: conflict-free
        }
    }
    __syncthreads();

    // coalesced flush: lanes span n -> 4 full 64B lines per store instruction
#pragma unroll
    for (int i = tid; i < BATCH * 64 * NPB; i += 1024) {  // 4096
        int b = i >> 10, o = (i >> 4) & 63, nl = i & 15;
        out[((size_t)(b * 64 + o)) * NNODES + nbase + nl] = u.res[b][o][nl];
    }
}

// ---------------- launcher --------------------------------------------------
extern "C" void kernel_launch(void* const* d_in, const int* in_sizes, int n_in,
                              void* d_out, int out_size, void* d_ws, size_t ws_size,
                              hipStream_t stream) {
    const float* x    = (const float*)d_in[0];
    const int*   adj  = (const int*)d_in[1];
    const float* vals = (const float*)d_in[2];
    const float* W    = (const float*)d_in[3];
    const float* bias = (const float*)d_in[4];
    float* out = (float*)d_out;

    const int* src = adj;
    const int* dst = adj + NEDGES;

    char* ws = (char*)d_ws;
    // layout: xT 4MB | sgb 4MB | dgb 8MB | scnt 256K | dcnt 256K  (~16.5MB)
    float* xT   = (float*)(ws);
    int*   sgb  = (int*)  (ws + (4 << 20));
    int2*  dgb  = (int2*) (ws + (8 << 20));
    int*   scnt = (int*)  (ws + (16 << 20));
    int*   dcnt = (int*)  (ws + (16 << 20) + (256 << 10));

    k_prep<<<BATCH * (NNODES / 64), 1024, 0, stream>>>(x, src, dst, vals,
                                                       xT, sgb, dgb, scnt, dcnt);
    k_main<<<NNODES / NPB, 1024, 0, stream>>>(xT, sgb, dgb, scnt, dcnt,
                                              W, bias, out);
}